// Round 9
// baseline (959.777 us; speedup 1.0000x reference)
//
#include <hip/hip_runtime.h>
#include <cstdint>
#include <cstddef>

typedef __bf16 bf16_t;
typedef __bf16 bf16x8 __attribute__((ext_vector_type(8)));
typedef __bf16 bf16x4 __attribute__((ext_vector_type(4)));
typedef float f32x4 __attribute__((ext_vector_type(4)));

#define T_TOKENS 8192
#define HID 1024
#define INTER 512
#define NEXP 64
#define TOPK 8
#define NROWS (T_TOKENS * TOPK) /* 65536 */
#define RT_TOK 16

typedef const unsigned int __attribute__((address_space(1)))* gptr_t;
typedef unsigned int __attribute__((address_space(3)))* lptr_t;

__device__ __forceinline__ void gload_lds16(const void* g, void* l) {
  __builtin_amdgcn_global_load_lds((gptr_t)g, (lptr_t)l, 16, 0, 0);
}

__device__ __forceinline__ f32x4 mfma16(bf16x8 a, bf16x8 b, f32x4 c) {
  return __builtin_amdgcn_mfma_f32_16x16x32_bf16(a, b, c, 0, 0, 0);
}

// bijective XCD chunk swizzle: consecutive work ids land on the same XCD
__device__ __forceinline__ int xcd_swizzle(int bid, int nwg) {
  int q = nwg >> 3;           // nwg is a multiple of 8 here
  int xcd = bid & 7, i = bid >> 3;
  return xcd * q + i;
}

// ---------------- combined weight transpose + f32->bf16 (w1 and w2 in one launch) ------
// grid dim3(16 ntile, 24 ktile, 64 expert): y<16 -> w1 (K=1024), y>=16 -> w2 (K=512).
// Also zeroes cnt/cnt2 (128 ints) so no separate memset dispatch is needed.
__global__ void transpose_cvt2_kernel(const float* __restrict__ w1, bf16_t* __restrict__ Wt1,
                                      const float* __restrict__ w2, bf16_t* __restrict__ Wt2,
                                      int* __restrict__ cntz) {
  const int tid = threadIdx.x;
  if (blockIdx.x == 0 && blockIdx.y == 0 && blockIdx.z == 0 && tid < 128) cntz[tid] = 0;

  const int e = blockIdx.z;
  const float* W; bf16_t* Wt; int K, k0;
  if (blockIdx.y < 16) {
    W = w1; Wt = Wt1; K = 1024; k0 = blockIdx.y * 64;
  } else {
    W = w2; Wt = Wt2; K = 512; k0 = (blockIdx.y - 16) * 64;
  }
  const int N = 1024;
  const int n0 = blockIdx.x * 64;

  __shared__ __align__(8) bf16_t tile[64][68];
  {
    const int r = tid >> 2, cq = tid & 3;
    const float* src = W + ((size_t)e * K + k0 + r) * N + n0 + cq * 16;
#pragma unroll
    for (int q = 0; q < 4; ++q) {
      float4 v = *(const float4*)(src + q * 4);
      bf16x4 b;
      b[0] = (bf16_t)v.x; b[1] = (bf16_t)v.y; b[2] = (bf16_t)v.z; b[3] = (bf16_t)v.w;
      *(bf16x4*)&tile[r][cq * 16 + q * 4] = b;
    }
  }
  __syncthreads();
  {
    const int nl = tid >> 2, kq = tid & 3;
    __align__(16) bf16_t tmp[16];
#pragma unroll
    for (int i = 0; i < 16; ++i) tmp[i] = tile[kq * 16 + i][nl];
    bf16_t* dst = Wt + ((size_t)e * N + n0 + nl) * K + k0 + kq * 16;
    *(bf16x8*)(dst + 0) = *(const bf16x8*)(tmp + 0);
    *(bf16x8*)(dst + 8) = *(const bf16x8*)(tmp + 8);
  }
}

// ---------------- router: 16 tokens/block; emits hb (bf16 hs) + direct global histogram -
// LDS exactly 80KB -> 2 blocks/CU (adding even 256B drops to 1 block/CU: R8 lesson).
__launch_bounds__(256, 2)
__global__ void router_kernel(const float* __restrict__ hs, const float* __restrict__ rw,
                              float* __restrict__ wval, int* __restrict__ widx,
                              bf16_t* __restrict__ hb, int* __restrict__ cnt) {
  const int t0 = blockIdx.x * RT_TOK;
  const int tid = threadIdx.x;
  const int lane = tid & 63, w = tid >> 6;
  __shared__ float hsl[RT_TOK][HID / 4][4];   // 64 KB
  __shared__ float part[4][RT_TOK][NEXP];     // 16 KB

  for (int i = tid; i < RT_TOK * (HID / 4); i += 256) {
    int t = i >> 8, c = i & 255;
    float4 v = ((const float4*)(hs + (size_t)(t0 + t) * HID))[c];
    *(float4*)&hsl[t][c][0] = v;
    bf16x4 o;
    o[0] = (bf16_t)v.x; o[1] = (bf16_t)v.y; o[2] = (bf16_t)v.z; o[3] = (bf16_t)v.w;
    *(bf16x4*)(hb + (size_t)(t0 + t) * HID + c * 4) = o;   // fused f32->bf16 conversion
  }
  __syncthreads();

  // wave w covers K range [w*256, w*256+256); lane = expert
  float acc[RT_TOK];
#pragma unroll
  for (int t = 0; t < RT_TOK; ++t) acc[t] = 0.f;
  const int kb = w * 256;
  for (int kc = 0; kc < 64; ++kc) {
    const int k = kb + kc * 4;
    float r0 = rw[(size_t)(k + 0) * NEXP + lane];
    float r1 = rw[(size_t)(k + 1) * NEXP + lane];
    float r2 = rw[(size_t)(k + 2) * NEXP + lane];
    float r3 = rw[(size_t)(k + 3) * NEXP + lane];
#pragma unroll
    for (int t = 0; t < RT_TOK; ++t) {
      float4 hv = *(const float4*)&hsl[t][(kb >> 2) + kc][0];
      acc[t] = fmaf(hv.x, r0, acc[t]);
      acc[t] = fmaf(hv.y, r1, acc[t]);
      acc[t] = fmaf(hv.z, r2, acc[t]);
      acc[t] = fmaf(hv.w, r3, acc[t]);
    }
  }
#pragma unroll
  for (int t = 0; t < RT_TOK; ++t) part[w][t][lane] = acc[t];
  __syncthreads();

  // wave w finalizes tokens w*4 .. w*4+3
  for (int j = 0; j < 4; ++j) {
    const int t = w * 4 + j;
    float logit = part[0][t][lane] + part[1][t][lane] + part[2][t][lane] + part[3][t][lane];
    float m = logit;
    for (int off = 32; off; off >>= 1) m = fmaxf(m, __shfl_xor(m, off));
    float ex = expf(logit - m);
    float Z = ex;
    for (int off = 32; off; off >>= 1) Z += __shfl_xor(Z, off);
    float p = ex / Z;
    float sum8 = 0.f;
    float outv[8]; int outi[8];
#pragma unroll
    for (int s = 0; s < 8; ++s) {
      float v = p; int idx = lane;
      for (int off = 32; off; off >>= 1) {
        float vv = __shfl_xor(v, off);
        int ii = __shfl_xor(idx, off);
        if (vv > v || (vv == v && ii < idx)) { v = vv; idx = ii; }
      }
      outv[s] = v; outi[s] = idx; sum8 += v;
      if (lane == idx) p = -1.f;
    }
    if (lane == 0) {
      float inv = 1.f / sum8;
#pragma unroll
      for (int s = 0; s < 8; ++s) {
        wval[(size_t)(t0 + t) * TOPK + s] = outv[s] * inv;
        widx[(size_t)(t0 + t) * TOPK + s] = outi[s];
        atomicAdd(&cnt[outi[s]], 1);   // direct global histogram (64 L2-hot counters)
      }
    }
  }
}

// ---------------- assign (scan fused): row_org[p] = original flat index ----------------
__global__ void assign_kernel(const int* __restrict__ widx, const int* __restrict__ cnt,
                              int* __restrict__ cnt2, int* __restrict__ row_org,
                              int* __restrict__ seg) {
  __shared__ int segl[NEXP];
  const int tid = threadIdx.x;
  if (tid < NEXP) {
    int a = 0;
    for (int j = 0; j < tid; ++j) a += cnt[j];   // 64-wide local prefix (L1-hot)
    segl[tid] = a;
    if (blockIdx.x == 0) {
      seg[tid] = a;
      if (tid == NEXP - 1) seg[NEXP] = a + cnt[NEXP - 1];
    }
  }
  __syncthreads();
  for (int i = blockIdx.x * blockDim.x + tid; i < NROWS; i += gridDim.x * blockDim.x) {
    int e = widx[i];
    int p = segl[e] + atomicAdd(&cnt2[e], 1);
    row_org[p] = i;
  }
}

// ---------------- GEMM1: gathered X @ Wgate/Wup, fused SiLU -> h (bf16) ----------------
// 8-wave phase-structured pipeline: BM=256, BN=128gate+128up, BK=64, dbuf LDS 128KB,
// 4 phases per K-tile, stage of kt+1 issued in phases 0-1 (prefetch distance ~3 phases).
// grid dim3(8 mtile, 4 ntile, 64 expert), swizzled; 512 threads.
__launch_bounds__(512, 2)
__global__ void gemm1_kernel(const bf16_t* __restrict__ hb, const bf16_t* __restrict__ Wt1,
                             const int* __restrict__ row_org, const int* __restrict__ seg,
                             bf16_t* __restrict__ h) {
  const int bid = blockIdx.x + gridDim.x * (blockIdx.y + gridDim.y * blockIdx.z);
  const int swz = xcd_swizzle(bid, 8 * 4 * NEXP);
  const int mt = swz & 7;
  const int nt = (swz >> 3) & 3;
  const int e = swz >> 5;

  const int ms = seg[e];
  const int sz = seg[e + 1] - ms;
  const int n0 = nt * 128;
  const int tid = threadIdx.x;
  const int lane = tid & 63;
  const int wid = tid >> 6;      // 0..7
  const int wm = wid >> 2;       // 0..1 -> rows wm*128
  const int wn = wid & 3;        // 0..3 -> cols wn*32 (paired gate/up)

  __shared__ __align__(16) bf16_t As[2][256 * 64];   // 2 x 32 KB
  __shared__ __align__(16) bf16_t Bs[2][256 * 64];   // 2 x 32 KB

  const int srow = tid >> 3;                 // 0..63
  const int cg = (tid & 7) ^ (srow & 7);     // pre-swizzled global 16B-chunk index

  size_t boff[4];
#pragma unroll
  for (int b = 0; b < 4; ++b) {
    int brow = b * 64 + srow;                                        // 0..255
    int n = (brow < 128) ? (n0 + brow) : (512 + n0 + (brow - 128));  // gate | up
    boff[b] = ((size_t)e * 1024 + n) * 1024 + cg * 8;
  }
  const int l15 = lane & 15, l4 = lane >> 4;

  for (int m0 = mt * 256; m0 < sz; m0 += 8 * 256) {
    size_t aoff[4];
#pragma unroll
    for (int a = 0; a < 4; ++a) {
      int row = a * 64 + srow;
      int idx = m0 + row; if (idx >= sz) idx = sz - 1;  // clamp: masked on store
      aoff[a] = (size_t)(row_org[ms + idx] >> 3) * HID + cg * 8;
    }
    f32x4 accg[8][2], accu[8][2];
#pragma unroll
    for (int mi = 0; mi < 8; ++mi)
#pragma unroll
      for (int gi = 0; gi < 2; ++gi) {
        accg[mi][gi] = (f32x4){0.f, 0.f, 0.f, 0.f};
        accu[mi][gi] = (f32x4){0.f, 0.f, 0.f, 0.f};
      }

    // prologue: K-tile 0 -> buf 0
#pragma unroll
    for (int a = 0; a < 4; ++a)
      gload_lds16(hb + aoff[a], (char*)&As[0][0] + a * 8192 + tid * 16);
#pragma unroll
    for (int a = 0; a < 4; ++a)
      gload_lds16(Wt1 + boff[a], (char*)&Bs[0][0] + a * 8192 + tid * 16);
    asm volatile("s_waitcnt vmcnt(0)\n\ts_barrier" ::: "memory");

    for (int kt = 0; kt < 16; ++kt) {
      const int b = kt & 1;
      const char* Ab = (const char*)&As[b][0];
      const char* Bb = (const char*)&Bs[b][0];
      const bool pf = (kt + 1 < 16);
      const int ko = (kt + 1) * 64;

      bf16x8 bfr[8];  // [kf*4 + {g0,g1,u0,u1}]
#pragma unroll
      for (int p = 0; p < 4; ++p) {
        const int mi0 = p * 2;
        if (p == 0) {
          // B-frags for the whole K-tile (reused by all mi phases)
#pragma unroll
          for (int kf = 0; kf < 2; ++kf) {
            const int ch = kf * 4 + l4;
#pragma unroll
            for (int gi = 0; gi < 2; ++gi) {
              int rg = wn * 32 + gi * 16 + l15;
              bfr[kf * 4 + gi] = *(const bf16x8*)(Bb + rg * 128 + ((ch ^ (rg & 7)) << 4));
              int ru = rg + 128;
              bfr[kf * 4 + 2 + gi] = *(const bf16x8*)(Bb + ru * 128 + ((ch ^ (ru & 7)) << 4));
            }
          }
        }
        bf16x8 af[4];  // [mi(2) x kf(2)]
#pragma unroll
        for (int mi = 0; mi < 2; ++mi)
#pragma unroll
          for (int kf = 0; kf < 2; ++kf) {
            int r = wm * 128 + (mi0 + mi) * 16 + l15;
            int ch = kf * 4 + l4;
            af[mi * 2 + kf] = *(const bf16x8*)(Ab + r * 128 + ((ch ^ (r & 7)) << 4));
          }
        if (pf && p == 0) {   // stage A of kt+1 -> buf b^1
#pragma unroll
          for (int a = 0; a < 4; ++a)
            gload_lds16(hb + aoff[a] + ko, (char*)&As[b ^ 1][0] + a * 8192 + tid * 16);
        }
        if (pf && p == 1) {   // stage B of kt+1 -> buf b^1
#pragma unroll
          for (int a = 0; a < 4; ++a)
            gload_lds16(Wt1 + boff[a] + ko, (char*)&Bs[b ^ 1][0] + a * 8192 + tid * 16);
        }
        __builtin_amdgcn_s_barrier();
        __builtin_amdgcn_s_setprio(1);
#pragma unroll
        for (int mi = 0; mi < 2; ++mi)
#pragma unroll
          for (int kf = 0; kf < 2; ++kf)
#pragma unroll
            for (int gi = 0; gi < 2; ++gi) {
              accg[mi0 + mi][gi] = mfma16(af[mi * 2 + kf], bfr[kf * 4 + gi], accg[mi0 + mi][gi]);
              accu[mi0 + mi][gi] = mfma16(af[mi * 2 + kf], bfr[kf * 4 + 2 + gi], accu[mi0 + mi][gi]);
            }
        __builtin_amdgcn_s_setprio(0);
        if (p == 3) {
          // gate: kt+1's 8 loads (the only outstanding ones) must have landed
          asm volatile("s_waitcnt vmcnt(0)" ::: "memory");
        }
        __builtin_amdgcn_s_barrier();
      }
    }
    // epilogue: h = silu(gate) * up
#pragma unroll
    for (int mi = 0; mi < 8; ++mi) {
#pragma unroll
      for (int j = 0; j < 4; ++j) {
        int mrow = wm * 128 + mi * 16 + l4 * 4 + j;
        int idx = m0 + mrow;
        if (idx < sz) {
          bf16_t* hrow = h + (size_t)(ms + idx) * INTER + n0 + wn * 32 + l15;
#pragma unroll
          for (int gi = 0; gi < 2; ++gi) {
            float g = accg[mi][gi][j];
            float u = accu[mi][gi][j];
            float s = g / (1.f + __expf(-g));
            hrow[gi * 16] = (bf16_t)(s * u);
          }
        }
      }
    }
  }
}

// ---------------- GEMM2: h @ Wdown -> expert_out (bf16) stored at UNPERMUTED row --------
// launch grid dim3(16 mtile, 8 ntile, 64 expert); swizzled (proven R5 structure)
__launch_bounds__(256, 2)
__global__ void gemm2_kernel(const bf16_t* __restrict__ h, const bf16_t* __restrict__ Wt2,
                             const int* __restrict__ row_org, const int* __restrict__ seg,
                             bf16_t* __restrict__ eo) {
  const int bid = blockIdx.x + gridDim.x * (blockIdx.y + gridDim.y * blockIdx.z);
  const int swz = xcd_swizzle(bid, 16 * 8 * NEXP);
  const int mt = swz & 15;
  const int nt = (swz >> 4) & 7;
  const int e = swz >> 7;

  const int ms = seg[e];
  const int sz = seg[e + 1] - ms;
  const int n0 = nt * 128;
  const int tid = threadIdx.x;
  const int lane = tid & 63;
  const int wid = tid >> 6;
  const int wm = wid >> 1, wn = wid & 1;
  __shared__ __align__(16) bf16_t As[128 * 64];
  __shared__ __align__(16) bf16_t Bs[128 * 64];
  const int srow = tid >> 3;
  const int cg = (tid & 7) ^ (srow & 7);
  size_t boff[4];
#pragma unroll
  for (int b = 0; b < 4; ++b) {
    int brow = b * 32 + srow;  // 0..127
    boff[b] = ((size_t)e * 1024 + n0 + brow) * INTER + cg * 8;
  }
  const int l15 = lane & 15, l4 = lane >> 4;

  for (int m0 = mt * 128; m0 < sz; m0 += 16 * 128) {
    size_t aoff[4];
#pragma unroll
    for (int a = 0; a < 4; ++a) {
      int row = a * 32 + srow;
      int idx = m0 + row; if (idx >= sz) idx = sz - 1;
      aoff[a] = (size_t)(ms + idx) * INTER + cg * 8;
    }
    f32x4 acc[4][4];
#pragma unroll
    for (int mi = 0; mi < 4; ++mi)
#pragma unroll
      for (int ni = 0; ni < 4; ++ni) acc[mi][ni] = (f32x4){0.f, 0.f, 0.f, 0.f};

    for (int kt = 0; kt < 8; ++kt) {
      const int ko = kt * 64;
      __syncthreads();
#pragma unroll
      for (int a = 0; a < 4; ++a)
        gload_lds16(h + aoff[a] + ko, (char*)As + a * 4096 + tid * 16);
#pragma unroll
      for (int b = 0; b < 4; ++b)
        gload_lds16(Wt2 + boff[b] + ko, (char*)Bs + b * 4096 + tid * 16);
      __syncthreads();
#pragma unroll
      for (int kf = 0; kf < 2; ++kf) {
        const int ch = kf * 4 + l4;
        bf16x8 af[4], bb[4];
#pragma unroll
        for (int mi = 0; mi < 4; ++mi) {
          int r = wm * 64 + mi * 16 + l15;
          af[mi] = *(const bf16x8*)((const char*)As + r * 128 + ((ch ^ (r & 7)) << 4));
        }
#pragma unroll
        for (int ni = 0; ni < 4; ++ni) {
          int r = wn * 64 + ni * 16 + l15;
          bb[ni] = *(const bf16x8*)((const char*)Bs + r * 128 + ((ch ^ (r & 7)) << 4));
        }
#pragma unroll
        for (int mi = 0; mi < 4; ++mi)
#pragma unroll
          for (int ni = 0; ni < 4; ++ni)
            acc[mi][ni] = mfma16(af[mi], bb[ni], acc[mi][ni]);
      }
    }
    // epilogue: plain bf16 store at unpermuted row (t*8+s); weight applied in unpermute
#pragma unroll
    for (int mi = 0; mi < 4; ++mi) {
#pragma unroll
      for (int j = 0; j < 4; ++j) {
        int mrow = wm * 64 + mi * 16 + l4 * 4 + j;
        int idx = m0 + mrow;
        if (idx < sz) {
          int org = row_org[ms + idx];
          bf16_t* orow = eo + (size_t)org * HID + n0 + wn * 64 + l15;
#pragma unroll
          for (int ni = 0; ni < 4; ++ni)
            orow[ni * 16] = (bf16_t)acc[mi][ni][j];
        }
      }
    }
  }
}

// ---------------- unpermute: out[t] = sum_s wval[t*8+s] * eo[t*8+s]; 2 tokens/block ------
__global__ void unpermute_kernel(const bf16_t* __restrict__ eo, const float* __restrict__ wval,
                                 float* __restrict__ out) {
  const int t = blockIdx.x * 2 + (threadIdx.x >> 7);
  const int c0 = (threadIdx.x & 127) * 8;  // 128 threads x 8 cols = 1024
  float w[8];
#pragma unroll
  for (int s = 0; s < 8; ++s) w[s] = wval[(size_t)t * 8 + s];
  float acc[8] = {0.f, 0.f, 0.f, 0.f, 0.f, 0.f, 0.f, 0.f};
#pragma unroll
  for (int s = 0; s < 8; ++s) {
    bf16x8 v = *(const bf16x8*)(eo + ((size_t)t * 8 + s) * HID + c0);
#pragma unroll
    for (int q = 0; q < 8; ++q) acc[q] = fmaf(w[s], (float)v[q], acc[q]);
  }
  *(float4*)(out + (size_t)t * HID + c0) = *(float4*)&acc[0];
  *(float4*)(out + (size_t)t * HID + c0 + 4) = *(float4*)&acc[4];
}

extern "C" void kernel_launch(void* const* d_in, const int* in_sizes, int n_in,
                              void* d_out, int out_size, void* d_ws, size_t ws_size,
                              hipStream_t stream) {
  (void)in_sizes; (void)n_in; (void)ws_size; (void)out_size;
  const float* hs = (const float*)d_in[0];   // [8192,1024]
  const float* rw = (const float*)d_in[1];   // [1024,64]
  const float* w1 = (const float*)d_in[2];   // [64,1024,1024]
  const float* w2 = (const float*)d_in[3];   // [64,512,1024]
  float* out = (float*)d_out;                // [8192,1024]

  char* p = (char*)d_ws;
  size_t off = 0;
  auto carve = [&](size_t bytes) {
    void* r = p + off;
    off = (off + bytes + 255) & ~(size_t)255;
    return r;
  };
  bf16_t* Wt1  = (bf16_t*)carve((size_t)NEXP * 1024 * 1024 * 2);  // 128 MB [e][n][k]
  bf16_t* Wt2  = (bf16_t*)carve((size_t)NEXP * 1024 * 512 * 2);   //  64 MB [e][n][k]
  bf16_t* hb   = (bf16_t*)carve((size_t)T_TOKENS * HID * 2);      //  16 MB
  bf16_t* hmid = (bf16_t*)carve((size_t)NROWS * INTER * 2);       //  64 MB
  float* wval  = (float*)carve((size_t)NROWS * 4);
  int* widx    = (int*)carve((size_t)NROWS * 4);
  int* row_org = (int*)carve((size_t)NROWS * 4);
  int* cnt     = (int*)carve(512);            // cnt[64] | cnt2[64], zeroed by transpose
  int* seg     = (int*)carve(66 * 4);
  int* cnt2    = cnt + 64;

  // expert_out [NROWS][HID] bf16 (128 MB) ALIASES Wt1: Wt1 is dead once gemm1
  // completes, and stream order serializes gemm1 -> gemm2 on every replay.
  bf16_t* eo = Wt1;

  transpose_cvt2_kernel<<<dim3(16, 24, 64), 256, 0, stream>>>(w1, Wt1, w2, Wt2, cnt);
  router_kernel<<<T_TOKENS / RT_TOK, 256, 0, stream>>>(hs, rw, wval, widx, hb, cnt);
  assign_kernel<<<128, 256, 0, stream>>>(widx, cnt, cnt2, row_org, seg);
  gemm1_kernel<<<dim3(8, 4, NEXP), 512, 0, stream>>>(hb, Wt1, row_org, seg, hmid);
  gemm2_kernel<<<dim3(16, 8, NEXP), 256, 0, stream>>>(hmid, Wt2, row_org, seg, eo);
  unpermute_kernel<<<T_TOKENS / 2, 256, 0, stream>>>(eo, wval, out);
}

// Round 10
// 598.687 us; speedup vs baseline: 1.6031x; 1.6031x over previous
//
#include <hip/hip_runtime.h>
#include <cstdint>
#include <cstddef>

typedef __bf16 bf16_t;
typedef __bf16 bf16x8 __attribute__((ext_vector_type(8)));
typedef __bf16 bf16x4 __attribute__((ext_vector_type(4)));
typedef float f32x4 __attribute__((ext_vector_type(4)));

#define T_TOKENS 8192
#define HID 1024
#define INTER 512
#define NEXP 64
#define TOPK 8
#define NROWS (T_TOKENS * TOPK) /* 65536 */
#define RT_TOK 16

typedef const unsigned int __attribute__((address_space(1)))* gptr_t;
typedef unsigned int __attribute__((address_space(3)))* lptr_t;

__device__ __forceinline__ void gload_lds16(const void* g, void* l) {
  __builtin_amdgcn_global_load_lds((gptr_t)g, (lptr_t)l, 16, 0, 0);
}

__device__ __forceinline__ f32x4 mfma16(bf16x8 a, bf16x8 b, f32x4 c) {
  return __builtin_amdgcn_mfma_f32_16x16x32_bf16(a, b, c, 0, 0, 0);
}

// bijective XCD chunk swizzle: consecutive work ids land on the same XCD
__device__ __forceinline__ int xcd_swizzle(int bid, int nwg) {
  int q = nwg >> 3;           // nwg is a multiple of 8 here
  int xcd = bid & 7, i = bid >> 3;
  return xcd * q + i;
}

// ---------------- combined weight transpose + f32->bf16 (w1 and w2 in one launch) ------
// grid dim3(16 ntile, 24 ktile, 64 expert): y<16 -> w1 (K=1024), y>=16 -> w2 (K=512).
// Also zeroes cnt/cnt2 (128 ints) so no separate memset dispatch is needed.
__global__ void transpose_cvt2_kernel(const float* __restrict__ w1, bf16_t* __restrict__ Wt1,
                                      const float* __restrict__ w2, bf16_t* __restrict__ Wt2,
                                      int* __restrict__ cntz) {
  const int tid = threadIdx.x;
  if (blockIdx.x == 0 && blockIdx.y == 0 && blockIdx.z == 0 && tid < 128) cntz[tid] = 0;

  const int e = blockIdx.z;
  const float* W; bf16_t* Wt; int K, k0;
  if (blockIdx.y < 16) {
    W = w1; Wt = Wt1; K = 1024; k0 = blockIdx.y * 64;
  } else {
    W = w2; Wt = Wt2; K = 512; k0 = (blockIdx.y - 16) * 64;
  }
  const int N = 1024;
  const int n0 = blockIdx.x * 64;

  __shared__ __align__(8) bf16_t tile[64][68];
  {
    const int r = tid >> 2, cq = tid & 3;
    const float* src = W + ((size_t)e * K + k0 + r) * N + n0 + cq * 16;
#pragma unroll
    for (int q = 0; q < 4; ++q) {
      float4 v = *(const float4*)(src + q * 4);
      bf16x4 b;
      b[0] = (bf16_t)v.x; b[1] = (bf16_t)v.y; b[2] = (bf16_t)v.z; b[3] = (bf16_t)v.w;
      *(bf16x4*)&tile[r][cq * 16 + q * 4] = b;
    }
  }
  __syncthreads();
  {
    const int nl = tid >> 2, kq = tid & 3;
    __align__(16) bf16_t tmp[16];
#pragma unroll
    for (int i = 0; i < 16; ++i) tmp[i] = tile[kq * 16 + i][nl];
    bf16_t* dst = Wt + ((size_t)e * N + n0 + nl) * K + k0 + kq * 16;
    *(bf16x8*)(dst + 0) = *(const bf16x8*)(tmp + 0);
    *(bf16x8*)(dst + 8) = *(const bf16x8*)(tmp + 8);
  }
}

// ---------------- router: 16 tokens/block; emits hb (bf16 hs); NO histogram here --------
// LDS exactly 80KB -> 2 blocks/CU. Histogram done by hist_kernel (block-reduced; a direct
// global-atomic histogram here cost 355us in R9 -- same-address device atomics serialize).
__launch_bounds__(256, 2)
__global__ void router_kernel(const float* __restrict__ hs, const float* __restrict__ rw,
                              float* __restrict__ wval, int* __restrict__ widx,
                              bf16_t* __restrict__ hb) {
  const int t0 = blockIdx.x * RT_TOK;
  const int tid = threadIdx.x;
  const int lane = tid & 63, w = tid >> 6;
  __shared__ float hsl[RT_TOK][HID / 4][4];   // 64 KB
  __shared__ float part[4][RT_TOK][NEXP];     // 16 KB

  for (int i = tid; i < RT_TOK * (HID / 4); i += 256) {
    int t = i >> 8, c = i & 255;
    float4 v = ((const float4*)(hs + (size_t)(t0 + t) * HID))[c];
    *(float4*)&hsl[t][c][0] = v;
    bf16x4 o;
    o[0] = (bf16_t)v.x; o[1] = (bf16_t)v.y; o[2] = (bf16_t)v.z; o[3] = (bf16_t)v.w;
    *(bf16x4*)(hb + (size_t)(t0 + t) * HID + c * 4) = o;   // fused f32->bf16 conversion
  }
  __syncthreads();

  // wave w covers K range [w*256, w*256+256); lane = expert
  float acc[RT_TOK];
#pragma unroll
  for (int t = 0; t < RT_TOK; ++t) acc[t] = 0.f;
  const int kb = w * 256;
  for (int kc = 0; kc < 64; ++kc) {
    const int k = kb + kc * 4;
    float r0 = rw[(size_t)(k + 0) * NEXP + lane];
    float r1 = rw[(size_t)(k + 1) * NEXP + lane];
    float r2 = rw[(size_t)(k + 2) * NEXP + lane];
    float r3 = rw[(size_t)(k + 3) * NEXP + lane];
#pragma unroll
    for (int t = 0; t < RT_TOK; ++t) {
      float4 hv = *(const float4*)&hsl[t][(kb >> 2) + kc][0];
      acc[t] = fmaf(hv.x, r0, acc[t]);
      acc[t] = fmaf(hv.y, r1, acc[t]);
      acc[t] = fmaf(hv.z, r2, acc[t]);
      acc[t] = fmaf(hv.w, r3, acc[t]);
    }
  }
#pragma unroll
  for (int t = 0; t < RT_TOK; ++t) part[w][t][lane] = acc[t];
  __syncthreads();

  // wave w finalizes tokens w*4 .. w*4+3
  for (int j = 0; j < 4; ++j) {
    const int t = w * 4 + j;
    float logit = part[0][t][lane] + part[1][t][lane] + part[2][t][lane] + part[3][t][lane];
    float m = logit;
    for (int off = 32; off; off >>= 1) m = fmaxf(m, __shfl_xor(m, off));
    float ex = expf(logit - m);
    float Z = ex;
    for (int off = 32; off; off >>= 1) Z += __shfl_xor(Z, off);
    float p = ex / Z;
    float sum8 = 0.f;
    float outv[8]; int outi[8];
#pragma unroll
    for (int s = 0; s < 8; ++s) {
      float v = p; int idx = lane;
      for (int off = 32; off; off >>= 1) {
        float vv = __shfl_xor(v, off);
        int ii = __shfl_xor(idx, off);
        if (vv > v || (vv == v && ii < idx)) { v = vv; idx = ii; }
      }
      outv[s] = v; outi[s] = idx; sum8 += v;
      if (lane == idx) p = -1.f;
    }
    if (lane == 0) {
      float inv = 1.f / sum8;
#pragma unroll
      for (int s = 0; s < 8; ++s) {
        wval[(size_t)(t0 + t) * TOPK + s] = outv[s] * inv;
        widx[(size_t)(t0 + t) * TOPK + s] = outi[s];
      }
    }
  }
}

// ---------------- histogram: block-local LDS hist, then 64 global atomics per block -----
__global__ void hist_kernel(const int* __restrict__ widx, int* __restrict__ cnt) {
  __shared__ int h[NEXP];
  if (threadIdx.x < NEXP) h[threadIdx.x] = 0;
  __syncthreads();
  for (int i = blockIdx.x * blockDim.x + threadIdx.x; i < NROWS; i += gridDim.x * blockDim.x)
    atomicAdd(&h[widx[i]], 1);
  __syncthreads();
  if (threadIdx.x < NEXP) atomicAdd(&cnt[threadIdx.x], h[threadIdx.x]);
}

// ---------------- assign (scan fused): row_org[p] = original flat index ----------------
__global__ void assign_kernel(const int* __restrict__ widx, const int* __restrict__ cnt,
                              int* __restrict__ cnt2, int* __restrict__ row_org,
                              int* __restrict__ seg) {
  __shared__ int segl[NEXP];
  const int tid = threadIdx.x;
  if (tid < NEXP) {
    int a = 0;
    for (int j = 0; j < tid; ++j) a += cnt[j];   // 64-wide local prefix (L1-hot)
    segl[tid] = a;
    if (blockIdx.x == 0) {
      seg[tid] = a;
      if (tid == NEXP - 1) seg[NEXP] = a + cnt[NEXP - 1];
    }
  }
  __syncthreads();
  for (int i = blockIdx.x * blockDim.x + tid; i < NROWS; i += gridDim.x * blockDim.x) {
    int e = widx[i];
    int p = segl[e] + atomicAdd(&cnt2[e], 1);
    row_org[p] = i;
  }
}

// ---------------- GEMM1: gathered X @ Wgate/Wup, fused SiLU -> h (bf16) ----------------
// launch grid dim3(16 mtile, 4 ntile, 64 expert); swizzled so consecutive m-tiles share an XCD
__launch_bounds__(256, 2)
__global__ void gemm1_kernel(const bf16_t* __restrict__ hb, const bf16_t* __restrict__ Wt1,
                             const int* __restrict__ row_org, const int* __restrict__ seg,
                             bf16_t* __restrict__ h) {
  const int bid = blockIdx.x + gridDim.x * (blockIdx.y + gridDim.y * blockIdx.z);
  const int swz = xcd_swizzle(bid, 16 * 4 * NEXP);
  const int mt = swz & 15;
  const int nt = (swz >> 4) & 3;
  const int e = swz >> 6;

  const int ms = seg[e];
  const int sz = seg[e + 1] - ms;
  const int n0 = nt * 128;
  const int tid = threadIdx.x;
  const int lane = tid & 63;
  const int wid = tid >> 6;
  const int wm = wid >> 1, wn = wid & 1;
  __shared__ __align__(16) bf16_t As[128 * 64];
  __shared__ __align__(16) bf16_t Bs[256 * 64];

  const int srow = tid >> 3;                 // 0..31
  const int cg = (tid & 7) ^ (srow & 7);     // pre-swizzled global 16B-chunk index

  size_t boff[8];
#pragma unroll
  for (int b = 0; b < 8; ++b) {
    int brow = b * 32 + srow;                                        // 0..255
    int n = (brow < 128) ? (n0 + brow) : (512 + n0 + (brow - 128));  // gate | up
    boff[b] = ((size_t)e * 1024 + n) * 1024 + cg * 8;
  }
  const int l15 = lane & 15, l4 = lane >> 4;

  for (int m0 = mt * 128; m0 < sz; m0 += 16 * 128) {
    size_t aoff[4];
#pragma unroll
    for (int a = 0; a < 4; ++a) {
      int row = a * 32 + srow;
      int idx = m0 + row; if (idx >= sz) idx = sz - 1;  // clamp: masked on store
      aoff[a] = (size_t)(row_org[ms + idx] >> 3) * HID + cg * 8;
    }
    f32x4 accg[4][4], accu[4][4];
#pragma unroll
    for (int mi = 0; mi < 4; ++mi)
#pragma unroll
      for (int ni = 0; ni < 4; ++ni) {
        accg[mi][ni] = (f32x4){0.f, 0.f, 0.f, 0.f};
        accu[mi][ni] = (f32x4){0.f, 0.f, 0.f, 0.f};
      }

    for (int kt = 0; kt < 16; ++kt) {
      const int ko = kt * 64;
      __syncthreads();
#pragma unroll
      for (int a = 0; a < 4; ++a)
        gload_lds16(hb + aoff[a] + ko, (char*)As + a * 4096 + tid * 16);
#pragma unroll
      for (int b = 0; b < 8; ++b)
        gload_lds16(Wt1 + boff[b] + ko, (char*)Bs + b * 4096 + tid * 16);
      __syncthreads();
#pragma unroll
      for (int kf = 0; kf < 2; ++kf) {
        const int ch = kf * 4 + l4;
        bf16x8 af[4], bg[4], bu[4];
#pragma unroll
        for (int mi = 0; mi < 4; ++mi) {
          int r = wm * 64 + mi * 16 + l15;
          af[mi] = *(const bf16x8*)((const char*)As + r * 128 + ((ch ^ (r & 7)) << 4));
        }
#pragma unroll
        for (int ni = 0; ni < 4; ++ni) {
          int rg = wn * 64 + ni * 16 + l15;
          bg[ni] = *(const bf16x8*)((const char*)Bs + rg * 128 + ((ch ^ (rg & 7)) << 4));
          int ru = rg + 128;
          bu[ni] = *(const bf16x8*)((const char*)Bs + ru * 128 + ((ch ^ (ru & 7)) << 4));
        }
#pragma unroll
        for (int mi = 0; mi < 4; ++mi)
#pragma unroll
          for (int ni = 0; ni < 4; ++ni) {
            accg[mi][ni] = mfma16(af[mi], bg[ni], accg[mi][ni]);
            accu[mi][ni] = mfma16(af[mi], bu[ni], accu[mi][ni]);
          }
      }
    }
    // epilogue: h = silu(gate) * up
#pragma unroll
    for (int mi = 0; mi < 4; ++mi) {
#pragma unroll
      for (int j = 0; j < 4; ++j) {
        int mrow = wm * 64 + mi * 16 + l4 * 4 + j;
        int idx = m0 + mrow;
        if (idx < sz) {
          bf16_t* hrow = h + (size_t)(ms + idx) * INTER + n0 + wn * 64 + l15;
#pragma unroll
          for (int ni = 0; ni < 4; ++ni) {
            float g = accg[mi][ni][j];
            float u = accu[mi][ni][j];
            float s = g / (1.f + __expf(-g));
            hrow[ni * 16] = (bf16_t)(s * u);
          }
        }
      }
    }
  }
}

// ---------------- GEMM2: h @ Wdown -> expert_out (bf16) stored at UNPERMUTED row --------
// launch grid dim3(16 mtile, 8 ntile, 64 expert); swizzled
__launch_bounds__(256, 2)
__global__ void gemm2_kernel(const bf16_t* __restrict__ h, const bf16_t* __restrict__ Wt2,
                             const int* __restrict__ row_org, const int* __restrict__ seg,
                             bf16_t* __restrict__ eo) {
  const int bid = blockIdx.x + gridDim.x * (blockIdx.y + gridDim.y * blockIdx.z);
  const int swz = xcd_swizzle(bid, 16 * 8 * NEXP);
  const int mt = swz & 15;
  const int nt = (swz >> 4) & 7;
  const int e = swz >> 7;

  const int ms = seg[e];
  const int sz = seg[e + 1] - ms;
  const int n0 = nt * 128;
  const int tid = threadIdx.x;
  const int lane = tid & 63;
  const int wid = tid >> 6;
  const int wm = wid >> 1, wn = wid & 1;
  __shared__ __align__(16) bf16_t As[128 * 64];
  __shared__ __align__(16) bf16_t Bs[128 * 64];
  const int srow = tid >> 3;
  const int cg = (tid & 7) ^ (srow & 7);
  size_t boff[4];
#pragma unroll
  for (int b = 0; b < 4; ++b) {
    int brow = b * 32 + srow;  // 0..127
    boff[b] = ((size_t)e * 1024 + n0 + brow) * INTER + cg * 8;
  }
  const int l15 = lane & 15, l4 = lane >> 4;

  for (int m0 = mt * 128; m0 < sz; m0 += 16 * 128) {
    size_t aoff[4];
#pragma unroll
    for (int a = 0; a < 4; ++a) {
      int row = a * 32 + srow;
      int idx = m0 + row; if (idx >= sz) idx = sz - 1;
      aoff[a] = (size_t)(ms + idx) * INTER + cg * 8;
    }
    f32x4 acc[4][4];
#pragma unroll
    for (int mi = 0; mi < 4; ++mi)
#pragma unroll
      for (int ni = 0; ni < 4; ++ni) acc[mi][ni] = (f32x4){0.f, 0.f, 0.f, 0.f};

    for (int kt = 0; kt < 8; ++kt) {
      const int ko = kt * 64;
      __syncthreads();
#pragma unroll
      for (int a = 0; a < 4; ++a)
        gload_lds16(h + aoff[a] + ko, (char*)As + a * 4096 + tid * 16);
#pragma unroll
      for (int b = 0; b < 4; ++b)
        gload_lds16(Wt2 + boff[b] + ko, (char*)Bs + b * 4096 + tid * 16);
      __syncthreads();
#pragma unroll
      for (int kf = 0; kf < 2; ++kf) {
        const int ch = kf * 4 + l4;
        bf16x8 af[4], bb[4];
#pragma unroll
        for (int mi = 0; mi < 4; ++mi) {
          int r = wm * 64 + mi * 16 + l15;
          af[mi] = *(const bf16x8*)((const char*)As + r * 128 + ((ch ^ (r & 7)) << 4));
        }
#pragma unroll
        for (int ni = 0; ni < 4; ++ni) {
          int r = wn * 64 + ni * 16 + l15;
          bb[ni] = *(const bf16x8*)((const char*)Bs + r * 128 + ((ch ^ (r & 7)) << 4));
        }
#pragma unroll
        for (int mi = 0; mi < 4; ++mi)
#pragma unroll
          for (int ni = 0; ni < 4; ++ni)
            acc[mi][ni] = mfma16(af[mi], bb[ni], acc[mi][ni]);
      }
    }
    // epilogue: plain bf16 store at unpermuted row (t*8+s); weight applied in unpermute
#pragma unroll
    for (int mi = 0; mi < 4; ++mi) {
#pragma unroll
      for (int j = 0; j < 4; ++j) {
        int mrow = wm * 64 + mi * 16 + l4 * 4 + j;
        int idx = m0 + mrow;
        if (idx < sz) {
          int org = row_org[ms + idx];
          bf16_t* orow = eo + (size_t)org * HID + n0 + wn * 64 + l15;
#pragma unroll
          for (int ni = 0; ni < 4; ++ni)
            orow[ni * 16] = (bf16_t)acc[mi][ni][j];
        }
      }
    }
  }
}

// ---------------- unpermute: out[t] = sum_s wval[t*8+s] * eo[t*8+s]; 2 tokens/block ------
__global__ void unpermute_kernel(const bf16_t* __restrict__ eo, const float* __restrict__ wval,
                                 float* __restrict__ out) {
  const int t = blockIdx.x * 2 + (threadIdx.x >> 7);
  const int c0 = (threadIdx.x & 127) * 8;  // 128 threads x 8 cols = 1024
  float w[8];
#pragma unroll
  for (int s = 0; s < 8; ++s) w[s] = wval[(size_t)t * 8 + s];
  float acc[8] = {0.f, 0.f, 0.f, 0.f, 0.f, 0.f, 0.f, 0.f};
#pragma unroll
  for (int s = 0; s < 8; ++s) {
    bf16x8 v = *(const bf16x8*)(eo + ((size_t)t * 8 + s) * HID + c0);
#pragma unroll
    for (int q = 0; q < 8; ++q) acc[q] = fmaf(w[s], (float)v[q], acc[q]);
  }
  *(float4*)(out + (size_t)t * HID + c0) = *(float4*)&acc[0];
  *(float4*)(out + (size_t)t * HID + c0 + 4) = *(float4*)&acc[4];
}

extern "C" void kernel_launch(void* const* d_in, const int* in_sizes, int n_in,
                              void* d_out, int out_size, void* d_ws, size_t ws_size,
                              hipStream_t stream) {
  (void)in_sizes; (void)n_in; (void)ws_size; (void)out_size;
  const float* hs = (const float*)d_in[0];   // [8192,1024]
  const float* rw = (const float*)d_in[1];   // [1024,64]
  const float* w1 = (const float*)d_in[2];   // [64,1024,1024]
  const float* w2 = (const float*)d_in[3];   // [64,512,1024]
  float* out = (float*)d_out;                // [8192,1024]

  char* p = (char*)d_ws;
  size_t off = 0;
  auto carve = [&](size_t bytes) {
    void* r = p + off;
    off = (off + bytes + 255) & ~(size_t)255;
    return r;
  };
  bf16_t* Wt1  = (bf16_t*)carve((size_t)NEXP * 1024 * 1024 * 2);  // 128 MB [e][n][k]
  bf16_t* Wt2  = (bf16_t*)carve((size_t)NEXP * 1024 * 512 * 2);   //  64 MB [e][n][k]
  bf16_t* hb   = (bf16_t*)carve((size_t)T_TOKENS * HID * 2);      //  16 MB
  bf16_t* hmid = (bf16_t*)carve((size_t)NROWS * INTER * 2);       //  64 MB
  float* wval  = (float*)carve((size_t)NROWS * 4);
  int* widx    = (int*)carve((size_t)NROWS * 4);
  int* row_org = (int*)carve((size_t)NROWS * 4);
  int* cnt     = (int*)carve(512);            // cnt[64] | cnt2[64], zeroed by transpose
  int* seg     = (int*)carve(66 * 4);
  int* cnt2    = cnt + 64;

  // expert_out [NROWS][HID] bf16 (128 MB) ALIASES Wt1: Wt1 is dead once gemm1
  // completes, and stream order serializes gemm1 -> gemm2 on every replay.
  bf16_t* eo = Wt1;

  transpose_cvt2_kernel<<<dim3(16, 24, 64), 256, 0, stream>>>(w1, Wt1, w2, Wt2, cnt);
  router_kernel<<<T_TOKENS / RT_TOK, 256, 0, stream>>>(hs, rw, wval, widx, hb);
  hist_kernel<<<128, 256, 0, stream>>>(widx, cnt);
  assign_kernel<<<128, 256, 0, stream>>>(widx, cnt, cnt2, row_org, seg);
  gemm1_kernel<<<dim3(16, 4, NEXP), 256, 0, stream>>>(hb, Wt1, row_org, seg, hmid);
  gemm2_kernel<<<dim3(16, 8, NEXP), 256, 0, stream>>>(hmid, Wt2, row_org, seg, eo);
  unpermute_kernel<<<T_TOKENS / 2, 256, 0, stream>>>(eo, wval, out);
}